// Round 1
// baseline (77.594 us; speedup 1.0000x reference)
//
#include <hip/hip_runtime.h>
#include <math.h>

// SE layer: x[32,256,64,64] f32, w1[16,256], w2[256,256]
// pooled = mean(x, HW); y = relu(pooled @ w1^T); outer = y⊗y (flat 256);
// s = sigmoid(outer @ w2^T); out = x * s[b,c]

#define B 32
#define C 256
#define HID 16
#define BD 256       // HID*HID
#define HW 4096      // 64*64

// ---------------- kernel 1: global average pool ----------------
// one block per (b,c) pair; 4096 contiguous floats each
__global__ __launch_bounds__(256) void pool_kernel(const float* __restrict__ x,
                                                   float* __restrict__ pooled) {
    const int bc = blockIdx.x;
    const float4* xp = reinterpret_cast<const float4*>(x + (size_t)bc * HW);
    const int t = threadIdx.x;
    float sum = 0.f;
#pragma unroll
    for (int k = 0; k < 4; ++k) {
        float4 v = xp[t + k * 256];
        sum += (v.x + v.y) + (v.z + v.w);
    }
    // wave-64 butterfly reduce
#pragma unroll
    for (int off = 32; off > 0; off >>= 1) sum += __shfl_down(sum, off, 64);
    __shared__ float ws[4];
    const int lane = t & 63, wid = t >> 6;
    if (lane == 0) ws[wid] = sum;
    __syncthreads();
    if (t == 0) {
        float tot = (ws[0] + ws[1]) + (ws[2] + ws[3]);
        pooled[bc] = tot * (1.0f / (float)HW);
    }
}

// ---------------- kernel 2: fc1 + relu + outer + fc2 + sigmoid ----------------
// one block per batch; 256 threads
__global__ __launch_bounds__(256) void fc_kernel(const float* __restrict__ pooled,
                                                 const float* __restrict__ w1,
                                                 const float* __restrict__ w2,
                                                 float* __restrict__ s_out) {
    const int b = blockIdx.x;
    const int t = threadIdx.x;
    __shared__ float pl[C];
    __shared__ float yv[HID];
    __shared__ float outer[BD];

    pl[t] = pooled[b * C + t];
    __syncthreads();

    if (t < HID) {
        float acc = 0.f;
        const float* w1r = w1 + t * C;
#pragma unroll 8
        for (int c = 0; c < C; ++c) acc += pl[c] * w1r[c];
        yv[t] = fmaxf(acc, 0.f);
    }
    __syncthreads();

    outer[t] = yv[t >> 4] * yv[t & 15];
    __syncthreads();

    // s[c] = sigmoid( sum_d outer[d] * w2[c, d] ); thread t = channel c
    const float4* w2r = reinterpret_cast<const float4*>(w2 + (size_t)t * BD);
    const float4* orow = reinterpret_cast<const float4*>(outer);
    float acc = 0.f;
#pragma unroll 8
    for (int d4 = 0; d4 < BD / 4; ++d4) {
        float4 w = w2r[d4];
        float4 o = orow[d4];
        acc += w.x * o.x + w.y * o.y + w.z * o.z + w.w * o.w;
    }
    s_out[b * C + t] = 1.0f / (1.0f + expf(-acc));
}

// ---------------- kernel 3: channel-wise scale ----------------
__global__ __launch_bounds__(256) void scale_kernel(const float* __restrict__ x,
                                                    const float* __restrict__ s,
                                                    float* __restrict__ out) {
    const int bc = blockIdx.x;
    const float sc = s[bc];
    const float4* xp = reinterpret_cast<const float4*>(x + (size_t)bc * HW);
    float4* op = reinterpret_cast<float4*>(out + (size_t)bc * HW);
    const int t = threadIdx.x;
#pragma unroll
    for (int k = 0; k < 4; ++k) {
        float4 v = xp[t + k * 256];
        v.x *= sc; v.y *= sc; v.z *= sc; v.w *= sc;
        op[t + k * 256] = v;
    }
}

extern "C" void kernel_launch(void* const* d_in, const int* in_sizes, int n_in,
                              void* d_out, int out_size, void* d_ws, size_t ws_size,
                              hipStream_t stream) {
    const float* x  = (const float*)d_in[0];
    const float* w1 = (const float*)d_in[1];
    const float* w2 = (const float*)d_in[2];
    float* out = (float*)d_out;

    float* pooled = (float*)d_ws;                  // B*C floats = 32 KB
    float* s      = (float*)d_ws + B * C;          // B*C floats

    pool_kernel<<<B * C, 256, 0, stream>>>(x, pooled);
    fc_kernel<<<B, 256, 0, stream>>>(pooled, w1, w2, s);
    scale_kernel<<<B * C, 256, 0, stream>>>(x, s, out);
}

// Round 4
// 77.473 us; speedup vs baseline: 1.0016x; 1.0016x over previous
//
#include <hip/hip_runtime.h>
#include <math.h>

// SE layer: x[32,256,64,64] f32, w1[16,256], w2[256,256]
// pooled = mean(x, HW); y = relu(pooled @ w1^T); outer = y⊗y (flat 256);
// s = sigmoid(outer @ w2^T); out = x * s[b,c]
//
// 3-kernel structure (known-good). Non-temporal stores for `out` so its
// write-allocations don't evict x from the 256MB L3 — x (134MB) stays
// L3-resident, so the scale kernel's re-read (and the pool read on
// subsequent graph replays) are L3 hits, not HBM.

#define B 32
#define C 256
#define HID 16
#define BD 256       // HID*HID
#define HW 4096      // 64*64

typedef float vf4 __attribute__((ext_vector_type(4)));

// ---------------- kernel 1: global average pool ----------------
// one block per (b,c) pair; 4096 contiguous floats each
__global__ __launch_bounds__(256) void pool_kernel(const float* __restrict__ x,
                                                   float* __restrict__ pooled) {
    const int bc = blockIdx.x;
    const vf4* xp = reinterpret_cast<const vf4*>(x + (size_t)bc * HW);
    const int t = threadIdx.x;
    float sum = 0.f;
#pragma unroll
    for (int k = 0; k < 4; ++k) {
        vf4 v = xp[t + k * 256];
        sum += (v.x + v.y) + (v.z + v.w);
    }
    // wave-64 butterfly reduce
#pragma unroll
    for (int off = 32; off > 0; off >>= 1) sum += __shfl_down(sum, off, 64);
    __shared__ float ws[4];
    const int lane = t & 63, wid = t >> 6;
    if (lane == 0) ws[wid] = sum;
    __syncthreads();
    if (t == 0) {
        float tot = (ws[0] + ws[1]) + (ws[2] + ws[3]);
        pooled[bc] = tot * (1.0f / (float)HW);
    }
}

// ---------------- kernel 2: fc1 + relu + outer + fc2 + sigmoid ----------------
// one block per batch; 256 threads
__global__ __launch_bounds__(256) void fc_kernel(const float* __restrict__ pooled,
                                                 const float* __restrict__ w1,
                                                 const float* __restrict__ w2,
                                                 float* __restrict__ s_out) {
    const int b = blockIdx.x;
    const int t = threadIdx.x;
    __shared__ float pl[C];
    __shared__ float yv[HID];
    __shared__ float outer[BD];

    pl[t] = pooled[b * C + t];
    __syncthreads();

    if (t < HID) {
        float acc = 0.f;
        const float* w1r = w1 + t * C;
#pragma unroll 8
        for (int c = 0; c < C; ++c) acc += pl[c] * w1r[c];
        yv[t] = fmaxf(acc, 0.f);
    }
    __syncthreads();

    outer[t] = yv[t >> 4] * yv[t & 15];
    __syncthreads();

    // s[c] = sigmoid( sum_d outer[d] * w2[c, d] ); thread t = channel c
    const vf4* w2r = reinterpret_cast<const vf4*>(w2 + (size_t)t * BD);
    const vf4* orow = reinterpret_cast<const vf4*>(outer);
    float acc = 0.f;
#pragma unroll 8
    for (int d4 = 0; d4 < BD / 4; ++d4) {
        vf4 w = w2r[d4];
        vf4 o = orow[d4];
        acc += w.x * o.x + w.y * o.y + w.z * o.z + w.w * o.w;
    }
    s_out[b * C + t] = 1.0f / (1.0f + expf(-acc));
}

// ---------------- kernel 3: channel-wise scale (nt stores) ----------------
__global__ __launch_bounds__(256) void scale_kernel(const float* __restrict__ x,
                                                    const float* __restrict__ s,
                                                    float* __restrict__ out) {
    const int bc = blockIdx.x;
    const float sc = s[bc];
    const vf4* xp = reinterpret_cast<const vf4*>(x + (size_t)bc * HW);
    vf4* op = reinterpret_cast<vf4*>(out + (size_t)bc * HW);
    const int t = threadIdx.x;
#pragma unroll
    for (int k = 0; k < 4; ++k) {
        vf4 v = xp[t + k * 256];
        v *= sc;
        __builtin_nontemporal_store(v, &op[t + k * 256]);
    }
}

extern "C" void kernel_launch(void* const* d_in, const int* in_sizes, int n_in,
                              void* d_out, int out_size, void* d_ws, size_t ws_size,
                              hipStream_t stream) {
    const float* x  = (const float*)d_in[0];
    const float* w1 = (const float*)d_in[1];
    const float* w2 = (const float*)d_in[2];
    float* out = (float*)d_out;

    float* pooled = (float*)d_ws;                  // B*C floats
    float* s      = (float*)d_ws + B * C;          // B*C floats

    pool_kernel<<<B * C, 256, 0, stream>>>(x, pooled);
    fc_kernel<<<B, 256, 0, stream>>>(pooled, w1, w2, s);
    scale_kernel<<<B * C, 256, 0, stream>>>(x, s, out);
}